// Round 2
// baseline (571.280 us; speedup 1.0000x reference)
//
#include <hip/hip_runtime.h>
#include <stdint.h>

// Problem constants
#define N_NODES 25000
#define N_EDGES 400000
#define OUT_ELEMS 3200000          // 25000 * 2 * 64 floats
// max total chunks: sum ceil(deg/8) <= (400000 + 7*25000)/8 = 71875
#define MAX_CHUNKS 72000

typedef __attribute__((ext_vector_type(8))) short short8;   // 8 bf16 = 4 VGPRs
typedef __attribute__((ext_vector_type(4))) float f32x4;    // MFMA accum

#define MFMA16(a, b, c) __builtin_amdgcn_mfma_f32_16x16x32_bf16((a), (b), (c), 0, 0, 0)

// fp32 -> bf16, round-to-nearest-even (weights / q / repe-store path)
__device__ __forceinline__ short bf16r(float x) {
    unsigned u = __float_as_uint(x);
    u += 0x7FFFu + ((u >> 16) & 1u);
    return (short)(u >> 16);
}
// fp32 -> bf16, round-half-up (hot edge path)
__device__ __forceinline__ short bfr(float x) {
    return (short)((__float_as_uint(x) + 0x8000u) >> 16);
}

// Sum over each 16-lane group via DPP butterfly (pure VALU, no DS traffic).
#define DPP_ADD(x, ctrl) \
    ((x) + __int_as_float(__builtin_amdgcn_update_dpp(0, __float_as_int(x), (ctrl), 0xF, 0xF, true)))
__device__ __forceinline__ float red16(float x) {
    x = DPP_ADD(x, 0xB1);    // quad_perm [1,0,3,2]  (xor 1)
    x = DPP_ADD(x, 0x4E);    // quad_perm [2,3,0,1]  (xor 2)
    x = DPP_ADD(x, 0x141);   // row_half_mirror      (8-group)
    x = DPP_ADD(x, 0x140);   // row_mirror           (16-group)
    return x;
}

// order-preserving float -> uint map (monotone): max over floats == umax over maps
__device__ __forceinline__ unsigned fmap(float x) {
    const unsigned u = __float_as_uint(x);
    return ((int)u >= 0) ? (u | 0x80000000u) : ~u;
}
#define MAPPED_NEG_INF 0x007FFFFFu   // fmap(-inf)

// B fragment for cols [colbase, colbase+16) of [64 x 64] row-major fp32 W.
// B layout: n = lane&15, k = (lane>>4)*8 + j (+32 per khalf). Validated R2/R3.
__device__ __forceinline__ short8 load_bfrag(const float* __restrict__ W,
                                             int colbase, int lane, int khalf) {
    const int n = colbase + (lane & 15);
    const int k0 = khalf * 32 + ((lane >> 4) << 3);
    short8 f;
    #pragma unroll
    for (int j = 0; j < 8; ++j) f[j] = bf16r(W[(k0 + j) * 64 + n]);
    return f;
}

// A fragment from LDS tile (16 rows padded to 72 shorts = 144 B). Validated R2/R3.
__device__ __forceinline__ short8 afrag(const short* S, int lane, int khalf) {
    return *(const short8*)&S[(lane & 15) * 72 + khalf * 32 + ((lane >> 4) << 3)];
}

// ---------- init: out buffer to mapped(-inf) + zero CSR counts ----------
__global__ __launch_bounds__(256) void init_kernel(unsigned* __restrict__ out_u,
                                                   int* __restrict__ counts) {
    const int i = blockIdx.x * 256 + threadIdx.x;   // grid covers OUT_ELEMS exactly
    out_u[i] = MAPPED_NEG_INF;
    if (i < N_NODES) counts[i] = 0;
}

// ---------- CSR build ----------
__global__ __launch_bounds__(256) void hist_kernel(const int* __restrict__ dst,
                                                   int* __restrict__ counts) {
    const int i = blockIdx.x * 256 + threadIdx.x;
    if (i < N_EDGES) atomicAdd(&counts[dst[i]], 1);
}

#define BPT 98   // 256*98 = 25088 >= 25000
__global__ __launch_bounds__(256) void scan_kernel(const int* __restrict__ counts,
                                                   int* __restrict__ offsets,
                                                   int* __restrict__ cursor,
                                                   int* __restrict__ chunkoff) {
    __shared__ int pd[256];   // edge-count prefix
    __shared__ int pc[256];   // chunk-count prefix
    const int t = threadIdx.x;
    const int base = t * BPT;
    int sd = 0, sc = 0;
    for (int j = 0; j < BPT; ++j) {
        const int idx = base + j;
        if (idx < N_NODES) {
            const int d = counts[idx];
            sd += d;
            sc += (d + 7) >> 3;
        }
    }
    pd[t] = sd; pc[t] = sc;
    __syncthreads();
    for (int d = 1; d < 256; d <<= 1) {
        const int ad = (t >= d) ? pd[t - d] : 0;
        const int ac = (t >= d) ? pc[t - d] : 0;
        __syncthreads();
        pd[t] += ad; pc[t] += ac;
        __syncthreads();
    }
    int rd = (t > 0) ? pd[t - 1] : 0;
    int rc = (t > 0) ? pc[t - 1] : 0;
    for (int j = 0; j < BPT; ++j) {
        const int idx = base + j;
        if (idx < N_NODES) {
            offsets[idx]  = rd;
            cursor[idx]   = rd;
            chunkoff[idx] = rc;
            const int d = counts[idx];
            rd += d;
            rc += (d + 7) >> 3;
        }
    }
    if (t == 255) { offsets[N_NODES] = pd[255]; chunkoff[N_NODES] = pc[255]; }
}

// chunk descriptors: .x = node v, .y = base_edge | (nvalid << 24)   (nvalid in 1..8)
__global__ __launch_bounds__(256) void fill_kernel(const int* __restrict__ offsets,
                                                   const int* __restrict__ chunkoff,
                                                   int2* __restrict__ chunk_desc) {
    const int v = blockIdx.x * 256 + threadIdx.x;
    if (v < N_NODES) {
        const int off0 = offsets[v];
        const int deg  = offsets[v + 1] - off0;
        const int nch  = (deg + 7) >> 3;
        const int co   = chunkoff[v];
        for (int c = 0; c < nch; ++c) {
            int nval = deg - (c << 3);
            if (nval > 8) nval = 8;
            int2 d;
            d.x = v;
            d.y = (off0 + (c << 3)) | (nval << 24);
            chunk_desc[co + c] = d;
        }
    }
}

__global__ __launch_bounds__(256) void scatter_kernel(
    const int* __restrict__ src, const int* __restrict__ dst,
    int* __restrict__ cursor, int* __restrict__ perm, int* __restrict__ srcs,
    int* __restrict__ csr_pos) {
    const int i = blockIdx.x * 256 + threadIdx.x;
    if (i < N_EDGES) {
        const int d = dst[i];
        const int pos = atomicAdd(&cursor[d], 1);
        perm[pos] = i;
        srcs[pos] = src[i];
        csr_pos[i] = pos;      // orig edge id -> CSR slot (for repe permute pass)
    }
}

// ---------- QQ = (h @ W_Q) * rownorm (MFMA) + fused weight-fragment prep ----------
// Stores QQ = Q * ||Q||_head so the edge kernel needs no norm computation:
//   score = q*k*(||k||*||q||+1e-6)+r  ~=  (q||q||)*(k||k||) + r   (err ~1e-5)
__global__ __launch_bounds__(256) void q_mfma_kernel(
    const float* __restrict__ h, const float* __restrict__ Wq,
    const float* __restrict__ Wk, const float* __restrict__ Wv,
    const float* __restrict__ Wr, float* __restrict__ Q, short8* __restrict__ fw)
{
    __shared__ short sH[64 * 72];
    const int t = threadIdx.x;
    const int lane = t & 63, w = t >> 6;
    const int wcol = w << 4;                 // this wave's head = w
    const int ln = lane & 15, lq = lane >> 4;
    const int base = blockIdx.x * 64;

    const short8 b0 = load_bfrag(Wq, wcol, lane, 0);
    const short8 b1 = load_bfrag(Wq, wcol, lane, 1);

    {
        const int r = t >> 2, c4 = (t & 3) << 4;
        int row = base + r; if (row > 49999) row = 49999;
        const float4* p = (const float4*)&h[row * 64 + c4];
        short tmp[16];
        #pragma unroll
        for (int i = 0; i < 4; ++i) {
            float4 x = p[i];
            tmp[4*i+0] = bf16r(x.x); tmp[4*i+1] = bf16r(x.y);
            tmp[4*i+2] = bf16r(x.z); tmp[4*i+3] = bf16r(x.w);
        }
        *(short8*)&sH[r * 72 + c4]     = *(short8*)&tmp[0];
        *(short8*)&sH[r * 72 + c4 + 8] = *(short8*)&tmp[8];
    }
    __syncthreads();

    #pragma unroll
    for (int m = 0; m < 4; ++m) {
        const short* Sm = &sH[(m << 4) * 72];
        short8 a0 = afrag(Sm, lane, 0);
        short8 a1 = afrag(Sm, lane, 1);
        f32x4 acc = {0.f, 0.f, 0.f, 0.f};
        acc = MFMA16(a0, b0, acc);
        acc = MFMA16(a1, b1, acc);
        #pragma unroll
        for (int reg = 0; reg < 4; ++reg) {
            const float qn = sqrtf(red16(acc[reg] * acc[reg]));  // ||Q[row, head w]||
            const int row = base + (m << 4) + (lq << 2) + reg;
            if (row < 50000) Q[row * 64 + wcol + ln] = acc[reg] * qn;
        }
    }

    if (blockIdx.x == 0) {   // weight fragments for downstream kernels
        fw[(w * 6 + 0) * 64 + lane] = load_bfrag(Wk, wcol, lane, 0);
        fw[(w * 6 + 1) * 64 + lane] = load_bfrag(Wk, wcol, lane, 1);
        fw[(w * 6 + 2) * 64 + lane] = load_bfrag(Wv, wcol, lane, 0);
        fw[(w * 6 + 3) * 64 + lane] = load_bfrag(Wv, wcol, lane, 1);
        fw[(w * 6 + 4) * 64 + lane] = load_bfrag(Wr, wcol, lane, 0);
        fw[(w * 6 + 5) * 64 + lane] = load_bfrag(Wr, wcol, lane, 1);
    }
}

// ---------- repe permute pass: coalesced e read -> bf16 repe, CSR-ordered write ----
// Converts the 205 MB random e-gather of the edge kernel into:
//   205 MB coalesced read here + 102 MB random bf16 write here (latency-insensitive)
//   + 102 MB coalesced read in the edge kernel.
// Layout: repe[(csr_pos*2 + n)*16 + col] = uint2{ bf(h0)|bf(h1)<<16, bf(h2)|bf(h3)<<16 }
__global__ __launch_bounds__(256) void repe_perm_kernel(
    const float* __restrict__ e, const int* __restrict__ csr_pos,
    const short8* __restrict__ fw, uint2* __restrict__ repe)
{
    const int t = threadIdx.x;
    const int lane = t & 63;
    const int g = (blockIdx.x << 2) + (t >> 6);   // wave id; 50000 waves exactly
    const int base8 = g << 3;
    const int ln = lane & 15, lq = lane >> 4;
    const int eloc = ln >> 1, nr = ln & 1;        // A-row: edge slot + group
    const int k0 = lq << 3;

    const float* __restrict__ ep = &e[((base8 + eloc) * 2 + nr) << 6];

    short8 a0, a1;
    #pragma unroll
    for (int half = 0; half < 2; ++half) {
        const int cb = (half << 5) + k0;
        const float4 e0 = *(const float4*)&ep[cb];
        const float4 e1 = *(const float4*)&ep[cb + 4];
        short8 tg;
        tg[0] = bfr(e0.x); tg[1] = bfr(e0.y); tg[2] = bfr(e0.z); tg[3] = bfr(e0.w);
        tg[4] = bfr(e1.x); tg[5] = bfr(e1.y); tg[6] = bfr(e1.z); tg[7] = bfr(e1.w);
        if (half == 0) a0 = tg; else a1 = tg;
    }

    const int p0 = csr_pos[base8 + (lq << 1)];       // C rows: el = lq*2 + (reg>>1)
    const int p1 = csr_pos[base8 + (lq << 1) + 1];

    f32x4 aR[4];
    #pragma unroll
    for (int hd = 0; hd < 4; ++hd) {
        f32x4 acc = {0.f, 0.f, 0.f, 0.f};
        acc = MFMA16(a0, fw[(hd * 6 + 4) * 64 + lane], acc);
        acc = MFMA16(a1, fw[(hd * 6 + 5) * 64 + lane], acc);
        aR[hd] = acc;
    }

    #pragma unroll
    for (int reg = 0; reg < 4; ++reg) {
        const int p = (reg & 2) ? p1 : p0;
        const int n = reg & 1;
        uint2 pk;
        pk.x = (unsigned)(unsigned short)bf16r(aR[0][reg])
             | ((unsigned)(unsigned short)bf16r(aR[1][reg]) << 16);
        pk.y = (unsigned)(unsigned short)bf16r(aR[2][reg])
             | ((unsigned)(unsigned short)bf16r(aR[3][reg]) << 16);
        repe[((p << 1) + n) * 16 + ln] = pk;    // 16 ln-lanes -> 128 B contiguous
    }
}

// ---------- edge kernel v3: CSR-coalesced repe, no e-gather, factored epilogue ----
// Clamped duplicate edges reproduce the last valid edge's msg exactly (k, v AND
// repe all clamped to the same edge) -> idempotent under max -> no masking needed.
__global__ __launch_bounds__(256, 4) void edge_csr_kernel(
    const float* __restrict__ h, const float* __restrict__ QQ,
    const int* __restrict__ srcs, const int* __restrict__ chunkoff,
    const int2* __restrict__ chunk_desc, const short8* __restrict__ fw,
    const uint2* __restrict__ repe, unsigned* __restrict__ out_u)
{
    const int t = threadIdx.x;
    const int lane = t & 63;
    const int g = (blockIdx.x << 2) + (t >> 6);
    if (g >= chunkoff[N_NODES]) return;

    const int2 dsc = chunk_desc[g];
    const int v    = dsc.x;
    const int base = dsc.y & 0xFFFFFF;
    const int nval = dsc.y >> 24;            // valid edges in this chunk, 1..8

    const int ln = lane & 15, lq = lane >> 4;
    const int eloc = ln >> 1, nr = ln & 1;   // this lane's A-row: edge slot + group
    const int k0 = lq << 3;

    const int elc = (eloc < nval - 1) ? eloc : (nval - 1);   // clamp -> duplicate of last edge
    const int s   = srcs[base + elc];

    // repe gather: coalesced (CSR-consecutive), clamped consistently with A-rows
    uint2 rp[4];
    #pragma unroll
    for (int reg = 0; reg < 4; ++reg) {
        int el = (lq << 1) + ((reg & 2) >> 1);
        if (el > nval - 1) el = nval - 1;
        rp[reg] = repe[(((base + el) << 1) + (reg & 1)) * 16 + ln];
    }

    // K/V weight fragments (16 x b128, L1/L2-hot)
    short8 bK0[4], bK1[4], bV0[4], bV1[4];
    #pragma unroll
    for (int hd = 0; hd < 4; ++hd) {
        bK0[hd] = fw[(hd * 6 + 0) * 64 + lane];
        bK1[hd] = fw[(hd * 6 + 1) * 64 + lane];
        bV0[hd] = fw[(hd * 6 + 2) * 64 + lane];
        bV1[hd] = fw[(hd * 6 + 3) * 64 + lane];
    }

    // direct A (relu diff) fragments — no LDS
    const float* __restrict__ hs  = &h[((s  << 1) + nr) << 6];
    const float* __restrict__ hdp = &h[((v  << 1) + nr) << 6];

    short8 afr[2];
    #pragma unroll
    for (int half = 0; half < 2; ++half) {
        const int cb = (half << 5) + k0;
        const float4 s0 = *(const float4*)&hs[cb];
        const float4 s1 = *(const float4*)&hs[cb + 4];
        const float4 d0 = *(const float4*)&hdp[cb];
        const float4 d1 = *(const float4*)&hdp[cb + 4];
        short8 ta;
        ta[0] = bfr(fmaxf(s0.x - d0.x, 0.f));
        ta[1] = bfr(fmaxf(s0.y - d0.y, 0.f));
        ta[2] = bfr(fmaxf(s0.z - d0.z, 0.f));
        ta[3] = bfr(fmaxf(s0.w - d0.w, 0.f));
        ta[4] = bfr(fmaxf(s1.x - d1.x, 0.f));
        ta[5] = bfr(fmaxf(s1.y - d1.y, 0.f));
        ta[6] = bfr(fmaxf(s1.z - d1.z, 0.f));
        ta[7] = bfr(fmaxf(s1.w - d1.w, 0.f));
        afr[half] = ta;
    }

    // QQ rows (Q pre-scaled by its head-norm; wave-invariant)
    float qq0[4], qq1[4];
    #pragma unroll
    for (int hd = 0; hd < 4; ++hd) {
        qq0[hd] = QQ[(v << 7) + (hd << 4) + ln];
        qq1[hd] = QQ[(v << 7) + 64 + (hd << 4) + ln];
    }

    const float NEG_INF = __uint_as_float(0xFF800000u);
    float rm0[4] = {NEG_INF, NEG_INF, NEG_INF, NEG_INF};
    float rm1[4] = {NEG_INF, NEG_INF, NEG_INF, NEG_INF};

    #pragma unroll
    for (int hd = 0; hd < 4; ++hd) {
        f32x4 aK = {0.f, 0.f, 0.f, 0.f}, aV = aK;
        aK = MFMA16(afr[0], bK0[hd], aK); aK = MFMA16(afr[1], bK1[hd], aK);
        aV = MFMA16(afr[0], bV0[hd], aV); aV = MFMA16(afr[1], bV1[hd], aV);

        #pragma unroll
        for (int reg = 0; reg < 4; ++reg) {
            const unsigned w32 = (hd < 2) ? rp[reg].x : rp[reg].y;
            const float aRv = (hd & 1) ? __uint_as_float(w32 & 0xFFFF0000u)
                                       : __uint_as_float(w32 << 16);
            const float kk = aK[reg];
            const float sk = red16(kk * kk);        // ||k||^2 over head's 16 cols
            const float qv = (reg & 1) ? qq1[hd] : qq0[hd];
            const float msg = (qv * kk * sqrtf(sk) + aRv) * aV[reg];
            if (reg & 1) rm1[hd] = fmaxf(rm1[hd], msg);
            else         rm0[hd] = fmaxf(rm0[hd], msg);
        }
    }

    // max across quads (disjoint edges per quad), then one atomicMax per lane
    #pragma unroll
    for (int hd = 0; hd < 4; ++hd) {
        rm0[hd] = fmaxf(rm0[hd], __shfl_xor(rm0[hd], 16));
        rm0[hd] = fmaxf(rm0[hd], __shfl_xor(rm0[hd], 32));
        rm1[hd] = fmaxf(rm1[hd], __shfl_xor(rm1[hd], 16));
        rm1[hd] = fmaxf(rm1[hd], __shfl_xor(rm1[hd], 32));
    }
    const float o0 = (lq == 0) ? rm0[0] : (lq == 1) ? rm0[1] : (lq == 2) ? rm0[2] : rm0[3];
    const float o1 = (lq == 0) ? rm1[0] : (lq == 1) ? rm1[1] : (lq == 2) ? rm1[2] : rm1[3];
    atomicMax(&out_u[(v << 7) + lane],      fmap(o0));
    atomicMax(&out_u[(v << 7) + 64 + lane], fmap(o1));
}

// ---------- fallback edge kernel (small workspace): v2 structure + factored epilogue
__global__ __launch_bounds__(256, 4) void edge_chunk_kernel(
    const float* __restrict__ h, const float* __restrict__ e,
    const float* __restrict__ QQ, const int* __restrict__ srcs,
    const int* __restrict__ perm, const int* __restrict__ chunkoff,
    const int2* __restrict__ chunk_desc, const short8* __restrict__ fw,
    unsigned* __restrict__ out_u)
{
    const int t = threadIdx.x;
    const int lane = t & 63;
    const int g = (blockIdx.x << 2) + (t >> 6);
    if (g >= chunkoff[N_NODES]) return;

    const int2 dsc = chunk_desc[g];
    const int v    = dsc.x;
    const int base = dsc.y & 0xFFFFFF;
    const int nval = dsc.y >> 24;

    const int ln = lane & 15, lq = lane >> 4;
    const int eloc = ln >> 1, nr = ln & 1;
    const int k0 = lq << 3;

    const int elc = (eloc < nval - 1) ? eloc : (nval - 1);
    const int ei  = base + elc;
    const int ed  = perm[ei];
    const int s   = srcs[ei];

    short8 bK0[4], bK1[4], bV0[4], bV1[4], bR0[4], bR1[4];
    #pragma unroll
    for (int hd = 0; hd < 4; ++hd) {
        bK0[hd] = fw[(hd * 6 + 0) * 64 + lane];
        bK1[hd] = fw[(hd * 6 + 1) * 64 + lane];
        bV0[hd] = fw[(hd * 6 + 2) * 64 + lane];
        bV1[hd] = fw[(hd * 6 + 3) * 64 + lane];
        bR0[hd] = fw[(hd * 6 + 4) * 64 + lane];
        bR1[hd] = fw[(hd * 6 + 5) * 64 + lane];
    }

    const float* __restrict__ hs  = &h[((s  << 1) + nr) << 6];
    const float* __restrict__ hdp = &h[((v  << 1) + nr) << 6];
    const float* __restrict__ ep  = &e[(((ed << 1) + nr) << 6)];

    short8 afr[2], gfr[2];
    #pragma unroll
    for (int half = 0; half < 2; ++half) {
        const int cb = (half << 5) + k0;
        const float4 s0 = *(const float4*)&hs[cb];
        const float4 s1 = *(const float4*)&hs[cb + 4];
        const float4 d0 = *(const float4*)&hdp[cb];
        const float4 d1 = *(const float4*)&hdp[cb + 4];
        const float4 e0 = *(const float4*)&ep[cb];
        const float4 e1 = *(const float4*)&ep[cb + 4];
        short8 ta, tg;
        ta[0] = bfr(fmaxf(s0.x - d0.x, 0.f));
        ta[1] = bfr(fmaxf(s0.y - d0.y, 0.f));
        ta[2] = bfr(fmaxf(s0.z - d0.z, 0.f));
        ta[3] = bfr(fmaxf(s0.w - d0.w, 0.f));
        ta[4] = bfr(fmaxf(s1.x - d1.x, 0.f));
        ta[5] = bfr(fmaxf(s1.y - d1.y, 0.f));
        ta[6] = bfr(fmaxf(s1.z - d1.z, 0.f));
        ta[7] = bfr(fmaxf(s1.w - d1.w, 0.f));
        tg[0] = bfr(e0.x); tg[1] = bfr(e0.y); tg[2] = bfr(e0.z); tg[3] = bfr(e0.w);
        tg[4] = bfr(e1.x); tg[5] = bfr(e1.y); tg[6] = bfr(e1.z); tg[7] = bfr(e1.w);
        afr[half] = ta;
        gfr[half] = tg;
    }

    float qq0[4], qq1[4];
    #pragma unroll
    for (int hd = 0; hd < 4; ++hd) {
        qq0[hd] = QQ[(v << 7) + (hd << 4) + ln];
        qq1[hd] = QQ[(v << 7) + 64 + (hd << 4) + ln];
    }

    const float NEG_INF = __uint_as_float(0xFF800000u);
    float rm0[4] = {NEG_INF, NEG_INF, NEG_INF, NEG_INF};
    float rm1[4] = {NEG_INF, NEG_INF, NEG_INF, NEG_INF};

    #pragma unroll
    for (int hd = 0; hd < 4; ++hd) {
        f32x4 aK = {0.f, 0.f, 0.f, 0.f}, aV = aK, aR = aK;
        aK = MFMA16(afr[0], bK0[hd], aK); aK = MFMA16(afr[1], bK1[hd], aK);
        aV = MFMA16(afr[0], bV0[hd], aV); aV = MFMA16(afr[1], bV1[hd], aV);
        aR = MFMA16(gfr[0], bR0[hd], aR); aR = MFMA16(gfr[1], bR1[hd], aR);

        #pragma unroll
        for (int reg = 0; reg < 4; ++reg) {
            const float kk = aK[reg];
            const float sk = red16(kk * kk);
            const float qv = (reg & 1) ? qq1[hd] : qq0[hd];
            const float msg = (qv * kk * sqrtf(sk) + aR[reg]) * aV[reg];
            if (reg & 1) rm1[hd] = fmaxf(rm1[hd], msg);
            else         rm0[hd] = fmaxf(rm0[hd], msg);
        }
    }

    #pragma unroll
    for (int hd = 0; hd < 4; ++hd) {
        rm0[hd] = fmaxf(rm0[hd], __shfl_xor(rm0[hd], 16));
        rm0[hd] = fmaxf(rm0[hd], __shfl_xor(rm0[hd], 32));
        rm1[hd] = fmaxf(rm1[hd], __shfl_xor(rm1[hd], 16));
        rm1[hd] = fmaxf(rm1[hd], __shfl_xor(rm1[hd], 32));
    }
    const float o0 = (lq == 0) ? rm0[0] : (lq == 1) ? rm0[1] : (lq == 2) ? rm0[2] : rm0[3];
    const float o1 = (lq == 0) ? rm1[0] : (lq == 1) ? rm1[1] : (lq == 2) ? rm1[2] : rm1[3];
    atomicMax(&out_u[(v << 7) + lane],      fmap(o0));
    atomicMax(&out_u[(v << 7) + 64 + lane], fmap(o1));
}

// ---------- final: unmap uint -> float in place; untouched (-inf) -> 0 ----------
__global__ __launch_bounds__(256) void final_kernel(unsigned* __restrict__ io) {
    const int i = blockIdx.x * 256 + threadIdx.x;   // grid covers OUT_ELEMS/4 exactly
    uint4* p = (uint4*)io;
    uint4 m = p[i];
    unsigned a, b, c, d;
    a = (m.x & 0x80000000u) ? (m.x ^ 0x80000000u) : ~m.x;
    b = (m.y & 0x80000000u) ? (m.y ^ 0x80000000u) : ~m.y;
    c = (m.z & 0x80000000u) ? (m.z ^ 0x80000000u) : ~m.z;
    d = (m.w & 0x80000000u) ? (m.w ^ 0x80000000u) : ~m.w;
    if (a == 0xFF800000u) a = 0u;   // zero in-degree -> 0 (DGL convention)
    if (b == 0xFF800000u) b = 0u;
    if (c == 0xFF800000u) c = 0u;
    if (d == 0xFF800000u) d = 0u;
    m.x = a; m.y = b; m.z = c; m.w = d;
    p[i] = m;
}

extern "C" void kernel_launch(void* const* d_in, const int* in_sizes, int n_in,
                              void* d_out, int out_size, void* d_ws, size_t ws_size,
                              hipStream_t stream) {
    const float* h  = (const float*)d_in[0];
    const float* e  = (const float*)d_in[1];
    const float* Wq = (const float*)d_in[2];
    const float* Wk = (const float*)d_in[3];
    const float* Wv = (const float*)d_in[4];
    const float* Wr = (const float*)d_in[5];
    const int*   src = (const int*)d_in[6];
    const int*   dst = (const int*)d_in[7];
    float* out = (float*)d_out;

    // workspace layout (4B units)
    float* Q        = (float*)d_ws;                        // 3,200,000 (stores QQ)
    int*   counts   = (int*)d_ws + 3200000;                // 25,000
    int*   offsets  = (int*)d_ws + 3225000;                // 25,001
    int*   cursor   = (int*)d_ws + 3250008;                // 25,000
    int*   perm     = (int*)d_ws + 3275008;                // 400,000
    int*   srcs     = (int*)d_ws + 3675008;                // 400,000
    short8* fw      = (short8*)((int*)d_ws + 4075008);     // 1536 x 16B = 6144 ints
    int*   chunkoff = (int*)d_ws + 4081152;                // 25,001
    int2*  chunk_desc = (int2*)((int*)d_ws + 4106154);     // 72,000 x 8B (8B-aligned)
    int*   csr_pos  = (int*)d_ws + 4250154;                // 400,000
    uint2* repe     = (uint2*)((int*)d_ws + 4650160);      // 400,008 edges x 256 B (16B-aligned)
    // end of repe region = 30,250,672 ints = 121,002,688 bytes
    const bool big_ws = ws_size >= 121002688ull;

    init_kernel<<<12500, 256, 0, stream>>>((unsigned*)out, counts);   // 12500*256 == OUT_ELEMS
    hist_kernel<<<1563, 256, 0, stream>>>(dst, counts);
    scan_kernel<<<1, 256, 0, stream>>>(counts, offsets, cursor, chunkoff);
    fill_kernel<<<98, 256, 0, stream>>>(offsets, chunkoff, chunk_desc);
    scatter_kernel<<<1563, 256, 0, stream>>>(src, dst, cursor, perm, srcs, csr_pos);
    q_mfma_kernel<<<782, 256, 0, stream>>>(h, Wq, Wk, Wv, Wr, Q, fw);
    if (big_ws) {
        repe_perm_kernel<<<12500, 256, 0, stream>>>(e, csr_pos, fw, repe);  // 50000 waves
        edge_csr_kernel<<<17969, 256, 0, stream>>>(h, Q, srcs, chunkoff,
                                                   chunk_desc, fw, repe, (unsigned*)out);
    } else {
        edge_chunk_kernel<<<17969, 256, 0, stream>>>(h, e, Q, srcs, perm,
                                                     chunkoff, chunk_desc, fw, (unsigned*)out);
    }
    final_kernel<<<3125, 256, 0, stream>>>((unsigned*)out);           // 3125*256*4 == OUT_ELEMS
}

// Round 3
// 534.853 us; speedup vs baseline: 1.0681x; 1.0681x over previous
//
#include <hip/hip_runtime.h>
#include <stdint.h>

// Problem constants
#define N_NODES 25000
#define N_EDGES 400000

typedef __attribute__((ext_vector_type(8))) short short8;   // 8 bf16 = 4 VGPRs
typedef __attribute__((ext_vector_type(4))) float f32x4;    // MFMA accum

#define MFMA16(a, b, c) __builtin_amdgcn_mfma_f32_16x16x32_bf16((a), (b), (c), 0, 0, 0)

// fp32 -> bf16, round-to-nearest-even (weights / q / msg-store path)
__device__ __forceinline__ short bf16r(float x) {
    unsigned u = __float_as_uint(x);
    u += 0x7FFFu + ((u >> 16) & 1u);
    return (short)(u >> 16);
}
// fp32 -> bf16, round-half-up (hot edge path)
__device__ __forceinline__ short bfr(float x) {
    return (short)((__float_as_uint(x) + 0x8000u) >> 16);
}

// Sum over each 16-lane group via DPP butterfly (pure VALU, no DS traffic).
#define DPP_ADD(x, ctrl) \
    ((x) + __int_as_float(__builtin_amdgcn_update_dpp(0, __float_as_int(x), (ctrl), 0xF, 0xF, true)))
__device__ __forceinline__ float red16(float x) {
    x = DPP_ADD(x, 0xB1);    // quad_perm [1,0,3,2]  (xor 1)
    x = DPP_ADD(x, 0x4E);    // quad_perm [2,3,0,1]  (xor 2)
    x = DPP_ADD(x, 0x141);   // row_half_mirror      (8-group)
    x = DPP_ADD(x, 0x140);   // row_mirror           (16-group)
    return x;
}

// B fragment for cols [colbase, colbase+16) of [64 x 64] row-major fp32 W.
// B layout: n = lane&15, k = (lane>>4)*8 + j (+32 per khalf). Validated R2/R3.
__device__ __forceinline__ short8 load_bfrag(const float* __restrict__ W,
                                             int colbase, int lane, int khalf) {
    const int n = colbase + (lane & 15);
    const int k0 = khalf * 32 + ((lane >> 4) << 3);
    short8 f;
    #pragma unroll
    for (int j = 0; j < 8; ++j) f[j] = bf16r(W[(k0 + j) * 64 + n]);
    return f;
}

// A fragment from LDS tile (16 rows padded to 72 shorts = 144 B). Validated R2/R3.
__device__ __forceinline__ short8 afrag(const short* S, int lane, int khalf) {
    return *(const short8*)&S[(lane & 15) * 72 + khalf * 32 + ((lane >> 4) << 3)];
}

// ---------- CSR build ----------
__global__ __launch_bounds__(256) void zero_counts_kernel(int* __restrict__ counts) {
    const int i = blockIdx.x * 256 + threadIdx.x;
    if (i < N_NODES) counts[i] = 0;
}

__global__ __launch_bounds__(256) void hist_kernel(const int* __restrict__ dst,
                                                   int* __restrict__ counts) {
    const int i = blockIdx.x * 256 + threadIdx.x;
    if (i < N_EDGES) atomicAdd(&counts[dst[i]], 1);
}

#define BPT 98   // 256*98 = 25088 >= 25000
__global__ __launch_bounds__(256) void scan_kernel(const int* __restrict__ counts,
                                                   int* __restrict__ offsets,
                                                   int* __restrict__ cursor) {
    __shared__ int part[256];
    const int t = threadIdx.x;
    const int base = t * BPT;
    int s = 0;
    for (int j = 0; j < BPT; ++j) {
        const int idx = base + j;
        if (idx < N_NODES) s += counts[idx];
    }
    part[t] = s;
    __syncthreads();
    for (int d = 1; d < 256; d <<= 1) {
        const int add = (t >= d) ? part[t - d] : 0;
        __syncthreads();
        part[t] += add;
        __syncthreads();
    }
    int run = (t > 0) ? part[t - 1] : 0;
    for (int j = 0; j < BPT; ++j) {
        const int idx = base + j;
        if (idx < N_NODES) {
            offsets[idx] = run;
            cursor[idx]  = run;
            run += counts[idx];
        }
    }
    if (t == 255) offsets[N_NODES] = part[255];
}

// csr_pos[orig_edge] = this edge's unique slot within its dst node's CSR range
__global__ __launch_bounds__(256) void scatter_pos_kernel(
    const int* __restrict__ dst, int* __restrict__ cursor,
    int* __restrict__ csr_pos) {
    const int i = blockIdx.x * 256 + threadIdx.x;
    if (i < N_EDGES) {
        const int pos = atomicAdd(&cursor[dst[i]], 1);
        csr_pos[i] = pos;
    }
}

// ---------- QQ = (h @ W_Q) * rownorm (MFMA) + fused weight-fragment prep ----------
// Stores QQ = Q * ||Q||_head so the edge kernel needs no norm recompute:
//   score = q*k*(||k||*||q||+1e-6)+r  ~=  (q||q||)*(k||k||) + r   (validated R2)
__global__ __launch_bounds__(256) void q_mfma_kernel(
    const float* __restrict__ h, const float* __restrict__ Wq,
    const float* __restrict__ Wk, const float* __restrict__ Wv,
    const float* __restrict__ Wr, float* __restrict__ Q, short8* __restrict__ fw)
{
    __shared__ short sH[64 * 72];
    const int t = threadIdx.x;
    const int lane = t & 63, w = t >> 6;
    const int wcol = w << 4;                 // this wave's head = w
    const int ln = lane & 15, lq = lane >> 4;
    const int base = blockIdx.x * 64;

    const short8 b0 = load_bfrag(Wq, wcol, lane, 0);
    const short8 b1 = load_bfrag(Wq, wcol, lane, 1);

    {
        const int r = t >> 2, c4 = (t & 3) << 4;
        int row = base + r; if (row > 49999) row = 49999;
        const float4* p = (const float4*)&h[row * 64 + c4];
        short tmp[16];
        #pragma unroll
        for (int i = 0; i < 4; ++i) {
            float4 x = p[i];
            tmp[4*i+0] = bf16r(x.x); tmp[4*i+1] = bf16r(x.y);
            tmp[4*i+2] = bf16r(x.z); tmp[4*i+3] = bf16r(x.w);
        }
        *(short8*)&sH[r * 72 + c4]     = *(short8*)&tmp[0];
        *(short8*)&sH[r * 72 + c4 + 8] = *(short8*)&tmp[8];
    }
    __syncthreads();

    #pragma unroll
    for (int m = 0; m < 4; ++m) {
        const short* Sm = &sH[(m << 4) * 72];
        short8 a0 = afrag(Sm, lane, 0);
        short8 a1 = afrag(Sm, lane, 1);
        f32x4 acc = {0.f, 0.f, 0.f, 0.f};
        acc = MFMA16(a0, b0, acc);
        acc = MFMA16(a1, b1, acc);
        #pragma unroll
        for (int reg = 0; reg < 4; ++reg) {
            const float qn = sqrtf(red16(acc[reg] * acc[reg]));  // ||Q[row, head w]||
            const int row = base + (m << 4) + (lq << 2) + reg;
            if (row < 50000) Q[row * 64 + wcol + ln] = acc[reg] * qn;
        }
    }

    if (blockIdx.x == 0) {   // weight fragments for the edge kernel
        fw[(w * 6 + 0) * 64 + lane] = load_bfrag(Wk, wcol, lane, 0);
        fw[(w * 6 + 1) * 64 + lane] = load_bfrag(Wk, wcol, lane, 1);
        fw[(w * 6 + 2) * 64 + lane] = load_bfrag(Wv, wcol, lane, 0);
        fw[(w * 6 + 3) * 64 + lane] = load_bfrag(Wv, wcol, lane, 1);
        fw[(w * 6 + 4) * 64 + lane] = load_bfrag(Wr, wcol, lane, 0);
        fw[(w * 6 + 5) * 64 + lane] = load_bfrag(Wr, wcol, lane, 1);
    }
}

// ---------- edge-order msg pass: ALL per-edge compute, coalesced e read ----------
// One wave per 8 consecutive edges (orig order -> e coalesced, no masking: 50000*8
// == N_EDGES exactly). h[src]/h[dst]/QQ gathers are L2-hot (h+QQ = 25.6 MB).
// Result msg (bf16, 4 heads packed per uint2) is scatter-written into CSR slots:
// 256 B/edge, random within a 102 MB IF$-resident buffer — fire-and-forget.
// Layout: msg[(pos*2 + n)*16 + col] = uint2{ bf(h0)|bf(h1)<<16, bf(h2)|bf(h3)<<16 }
__global__ __launch_bounds__(256, 4) void edge_msg_kernel(
    const float* __restrict__ h, const float* __restrict__ e,
    const float* __restrict__ QQ, const int* __restrict__ src,
    const int* __restrict__ dst, const int* __restrict__ csr_pos,
    const short8* __restrict__ fw, uint2* __restrict__ msg)
{
    const int t = threadIdx.x;
    const int lane = t & 63;
    const int g = (blockIdx.x << 2) + (t >> 6);   // wave id; 50000 waves exactly
    const int g8 = g << 3;
    const int ln = lane & 15, lq = lane >> 4;
    const int eloc = ln >> 1, nr = ln & 1;        // this lane's A-row: edge slot + group
    const int k0 = lq << 3;

    // A-row sources (per-lane edge): diff = relu(h[src]-h[dst]), plus raw e row
    const int sA = src[g8 + eloc];
    const int dA = dst[g8 + eloc];
    const float* __restrict__ hs  = &h[((sA << 1) + nr) << 6];
    const float* __restrict__ hdp = &h[((dA << 1) + nr) << 6];
    const float* __restrict__ ep  = &e[(((g8 + eloc) << 1) + nr) << 6];

    short8 afr[2], gfr[2];
    #pragma unroll
    for (int half = 0; half < 2; ++half) {
        const int cb = (half << 5) + k0;
        const float4 s0 = *(const float4*)&hs[cb];
        const float4 s1 = *(const float4*)&hs[cb + 4];
        const float4 d0 = *(const float4*)&hdp[cb];
        const float4 d1 = *(const float4*)&hdp[cb + 4];
        const float4 e0 = *(const float4*)&ep[cb];
        const float4 e1 = *(const float4*)&ep[cb + 4];
        short8 ta, tg;
        ta[0] = bfr(fmaxf(s0.x - d0.x, 0.f));
        ta[1] = bfr(fmaxf(s0.y - d0.y, 0.f));
        ta[2] = bfr(fmaxf(s0.z - d0.z, 0.f));
        ta[3] = bfr(fmaxf(s0.w - d0.w, 0.f));
        ta[4] = bfr(fmaxf(s1.x - d1.x, 0.f));
        ta[5] = bfr(fmaxf(s1.y - d1.y, 0.f));
        ta[6] = bfr(fmaxf(s1.z - d1.z, 0.f));
        ta[7] = bfr(fmaxf(s1.w - d1.w, 0.f));
        tg[0] = bfr(e0.x); tg[1] = bfr(e0.y); tg[2] = bfr(e0.z); tg[3] = bfr(e0.w);
        tg[4] = bfr(e1.x); tg[5] = bfr(e1.y); tg[6] = bfr(e1.z); tg[7] = bfr(e1.w);
        afr[half] = ta;
        gfr[half] = tg;
    }

    // epilogue metadata for this lane's two C-row edges (C row rl=lq*4+reg ->
    // edge el = lq*2+(reg>>1), n = reg&1; validated R1/R2)
    const int e0i = g8 + (lq << 1), e1i = e0i + 1;
    const int d0 = dst[e0i], d1 = dst[e1i];
    const int p0 = csr_pos[e0i], p1 = csr_pos[e1i];

    // QQ gathers (L2-hot): qv for (edge, n, head) at this lane's col ln
    float qv_e0n0[4], qv_e0n1[4], qv_e1n0[4], qv_e1n1[4];
    #pragma unroll
    for (int hd = 0; hd < 4; ++hd) {
        qv_e0n0[hd] = QQ[(d0 << 7) + (hd << 4) + ln];
        qv_e0n1[hd] = QQ[(d0 << 7) + 64 + (hd << 4) + ln];
        qv_e1n0[hd] = QQ[(d1 << 7) + (hd << 4) + ln];
        qv_e1n1[hd] = QQ[(d1 << 7) + 64 + (hd << 4) + ln];
    }

    // K, V, R for all 4 heads (24 MFMAs)
    f32x4 aK[4], aV[4], aR[4];
    #pragma unroll
    for (int hd = 0; hd < 4; ++hd) {
        f32x4 k = {0.f, 0.f, 0.f, 0.f}, vv = k, r = k;
        k  = MFMA16(afr[0], fw[(hd * 6 + 0) * 64 + lane], k);
        k  = MFMA16(afr[1], fw[(hd * 6 + 1) * 64 + lane], k);
        vv = MFMA16(afr[0], fw[(hd * 6 + 2) * 64 + lane], vv);
        vv = MFMA16(afr[1], fw[(hd * 6 + 3) * 64 + lane], vv);
        r  = MFMA16(gfr[0], fw[(hd * 6 + 4) * 64 + lane], r);
        r  = MFMA16(gfr[1], fw[(hd * 6 + 5) * 64 + lane], r);
        aK[hd] = k; aV[hd] = vv; aR[hd] = r;
    }

    // per C-row: msg = (qq * k * ||k|| + r) * v, packed bf16 x 4 heads -> CSR slot
    #pragma unroll
    for (int reg = 0; reg < 4; ++reg) {
        float m[4];
        #pragma unroll
        for (int hd = 0; hd < 4; ++hd) {
            const float kk = aK[hd][reg];
            const float nk = sqrtf(red16(kk * kk));   // ||k|| over head's 16 cols
            const float qv = (reg == 0) ? qv_e0n0[hd] :
                             (reg == 1) ? qv_e0n1[hd] :
                             (reg == 2) ? qv_e1n0[hd] : qv_e1n1[hd];
            m[hd] = (qv * kk * nk + aR[hd][reg]) * aV[hd][reg];
        }
        uint2 pk;
        pk.x = (unsigned)(unsigned short)bf16r(m[0])
             | ((unsigned)(unsigned short)bf16r(m[1]) << 16);
        pk.y = (unsigned)(unsigned short)bf16r(m[2])
             | ((unsigned)(unsigned short)bf16r(m[3]) << 16);
        const int p = (reg & 2) ? p1 : p0;
        msg[(((p << 1) + (reg & 1)) << 4) + ln] = pk;   // 256 B/edge contiguous
    }
}

// ---------- CSR reduce: coalesced streaming max, direct out write ----------
// One wave per node; its msg rows are CSR-contiguous (deg * 256 B sequential).
// lane = n*32 + ph*16 + ln: reads uint (2 packed heads) at
//   msg_u[pos*64 + n*32 + ln*2 + ph]; per pos the wave reads 256 B coalesced.
__global__ __launch_bounds__(256) void reduce_kernel(
    const unsigned* __restrict__ msg_u, const int* __restrict__ offsets,
    float* __restrict__ out)
{
    const int t = threadIdx.x;
    const int lane = t & 63;
    const int v = (blockIdx.x << 2) + (t >> 6);   // 25000 waves exactly
    const int off0 = offsets[v], off1 = offsets[v + 1];
    const int n = lane >> 5, ph = (lane >> 4) & 1, ln = lane & 15;
    const unsigned* __restrict__ p = msg_u + ((n << 5) + (ln << 1) + ph);

    const float NEG_INF = __uint_as_float(0xFF800000u);
    float m0 = NEG_INF, m1 = NEG_INF;

    int pos = off0;
    for (; pos + 4 <= off1; pos += 4) {       // 4 independent loads in flight
        const unsigned u0 = p[(pos + 0) << 6];
        const unsigned u1 = p[(pos + 1) << 6];
        const unsigned u2 = p[(pos + 2) << 6];
        const unsigned u3 = p[(pos + 3) << 6];
        m0 = fmaxf(m0, __uint_as_float(u0 << 16));
        m1 = fmaxf(m1, __uint_as_float(u0 & 0xFFFF0000u));
        m0 = fmaxf(m0, __uint_as_float(u1 << 16));
        m1 = fmaxf(m1, __uint_as_float(u1 & 0xFFFF0000u));
        m0 = fmaxf(m0, __uint_as_float(u2 << 16));
        m1 = fmaxf(m1, __uint_as_float(u2 & 0xFFFF0000u));
        m0 = fmaxf(m0, __uint_as_float(u3 << 16));
        m1 = fmaxf(m1, __uint_as_float(u3 & 0xFFFF0000u));
    }
    for (; pos < off1; ++pos) {
        const unsigned u = p[pos << 6];
        m0 = fmaxf(m0, __uint_as_float(u << 16));
        m1 = fmaxf(m1, __uint_as_float(u & 0xFFFF0000u));
    }
    if (off0 == off1) { m0 = 0.f; m1 = 0.f; }   // zero in-degree -> 0 (DGL)

    // lo word = head 2*ph, hi word = head 2*ph+1; out col = n*64 + head*16 + ln
    const int col = (n << 6) + (ph << 5) + ln;
    out[(v << 7) + col]      = m0;
    out[(v << 7) + col + 16] = m1;
}

extern "C" void kernel_launch(void* const* d_in, const int* in_sizes, int n_in,
                              void* d_out, int out_size, void* d_ws, size_t ws_size,
                              hipStream_t stream) {
    const float* h  = (const float*)d_in[0];
    const float* e  = (const float*)d_in[1];
    const float* Wq = (const float*)d_in[2];
    const float* Wk = (const float*)d_in[3];
    const float* Wv = (const float*)d_in[4];
    const float* Wr = (const float*)d_in[5];
    const int*   src = (const int*)d_in[6];
    const int*   dst = (const int*)d_in[7];
    float* out = (float*)d_out;

    // workspace layout (4B units), ~117.1 MB total (ws >= 121 MB proven in R2)
    float* Q       = (float*)d_ws;                      // 3,200,000 (stores QQ)
    int*   counts  = (int*)d_ws + 3200000;              // 25,000
    int*   offsets = (int*)d_ws + 3225000;              // 25,001
    int*   cursor  = (int*)d_ws + 3250008;              // 25,000
    int*   csr_pos = (int*)d_ws + 3275008;              // 400,000
    short8* fw     = (short8*)((int*)d_ws + 3675008);   // 1536 x 16B = 6,144 ints
    uint2* msg     = (uint2*)((int*)d_ws + 3681152);    // 400,000 edges x 256 B

    zero_counts_kernel<<<98, 256, 0, stream>>>(counts);
    hist_kernel<<<1563, 256, 0, stream>>>(dst, counts);
    scan_kernel<<<1, 256, 0, stream>>>(counts, offsets, cursor);
    scatter_pos_kernel<<<1563, 256, 0, stream>>>(dst, cursor, csr_pos);
    q_mfma_kernel<<<782, 256, 0, stream>>>(h, Wq, Wk, Wv, Wr, Q, fw);
    edge_msg_kernel<<<12500, 256, 0, stream>>>(h, e, Q, src, dst, csr_pos, fw, msg);
    reduce_kernel<<<6250, 256, 0, stream>>>((const unsigned*)msg, offsets, out);
}

// Round 4
// 439.480 us; speedup vs baseline: 1.2999x; 1.2170x over previous
//
#include <hip/hip_runtime.h>
#include <stdint.h>

// Problem constants
#define N_NODES 25000
#define N_EDGES 400000

typedef __attribute__((ext_vector_type(8))) short short8;   // 8 bf16 = 4 VGPRs
typedef __attribute__((ext_vector_type(4))) float f32x4;    // MFMA accum

#define MFMA16(a, b, c) __builtin_amdgcn_mfma_f32_16x16x32_bf16((a), (b), (c), 0, 0, 0)

// fp32 -> bf16, round-to-nearest-even (weights / q / node-block path)
__device__ __forceinline__ short bf16r(float x) {
    unsigned u = __float_as_uint(x);
    u += 0x7FFFu + ((u >> 16) & 1u);
    return (short)(u >> 16);
}
// fp32 -> bf16, round-half-up (hot edge path)
__device__ __forceinline__ short bfr(float x) {
    return (short)((__float_as_uint(x) + 0x8000u) >> 16);
}

// Sum over each 16-lane group via DPP butterfly (pure VALU, no DS traffic).
#define DPP_ADD(x, ctrl) \
    ((x) + __int_as_float(__builtin_amdgcn_update_dpp(0, __float_as_int(x), (ctrl), 0xF, 0xF, true)))
__device__ __forceinline__ float red16(float x) {
    x = DPP_ADD(x, 0xB1);    // quad_perm [1,0,3,2]  (xor 1)
    x = DPP_ADD(x, 0x4E);    // quad_perm [2,3,0,1]  (xor 2)
    x = DPP_ADD(x, 0x141);   // row_half_mirror      (8-group)
    x = DPP_ADD(x, 0x140);   // row_mirror           (16-group)
    return x;
}

// order-preserving float -> uint map (monotone): max over floats == umax over maps
__device__ __forceinline__ unsigned fmap(float x) {
    const unsigned u = __float_as_uint(x);
    return ((int)u >= 0) ? (u | 0x80000000u) : ~u;
}
#define MAPPED_NEG_INF 0x007FFFFFu   // fmap(-inf); untouched rows -> 0 in final

// bf16 pair (packed u32) -> one float by parity
__device__ __forceinline__ float pickbf(unsigned u, int odd) {
    return __uint_as_float(odd ? (u & 0xFFFF0000u) : (u << 16));
}
// relu(s - d) on a packed bf16 pair, repacked to bf16 pair
__device__ __forceinline__ unsigned drelu_pack(unsigned s, unsigned d) {
    const float slo = __uint_as_float(s << 16);
    const float shi = __uint_as_float(s & 0xFFFF0000u);
    const float dlo = __uint_as_float(d << 16);
    const float dhi = __uint_as_float(d & 0xFFFF0000u);
    const unsigned lo = (unsigned short)bfr(fmaxf(slo - dlo, 0.f));
    const unsigned hi = (unsigned short)bfr(fmaxf(shi - dhi, 0.f));
    return lo | (hi << 16);
}

// B fragment for cols [colbase, colbase+16) of [64 x 64] row-major fp32 W.
// B layout: n = lane&15, k = (lane>>4)*8 + j (+32 per khalf). Validated R2/R3.
__device__ __forceinline__ short8 load_bfrag(const float* __restrict__ W,
                                             int colbase, int lane, int khalf) {
    const int n = colbase + (lane & 15);
    const int k0 = khalf * 32 + ((lane >> 4) << 3);
    short8 f;
    #pragma unroll
    for (int j = 0; j < 8; ++j) f[j] = bf16r(W[(k0 + j) * 64 + n]);
    return f;
}

// A fragment from LDS tile (16 rows padded to 72 shorts = 144 B). Validated R2/R3.
__device__ __forceinline__ short8 afrag(const short* S, int lane, int khalf) {
    return *(const short8*)&S[(lane & 15) * 72 + khalf * 32 + ((lane >> 4) << 3)];
}

// ---------- init: out buffer to mapped(-inf) ----------
__global__ __launch_bounds__(256) void init_kernel(unsigned* __restrict__ out_u) {
    const int i = blockIdx.x * 256 + threadIdx.x;   // grid covers OUT elems exactly
    out_u[i] = MAPPED_NEG_INF;
}

// ---------- q_mfma: NB pack (bf16 h + bf16 QQ per node) + weight fragments ----------
// NB[v] is a 512 B block (128 u32): [h n0 (64 bf16) | h n1 | qq n0 | qq n1]
// QQ = Q * ||Q||_head (factored epilogue, validated R2):
//   score = q*k*(||k||*||q||+1e-6)+r  ~=  (q||q||)*(k||k||) + r
__global__ __launch_bounds__(256) void q_mfma_kernel(
    const float* __restrict__ h, const float* __restrict__ Wq,
    const float* __restrict__ Wk, const float* __restrict__ Wv,
    const float* __restrict__ Wr, unsigned* __restrict__ NB, short8* __restrict__ fw)
{
    __shared__ short sH[64 * 72];
    const int t = threadIdx.x;
    const int lane = t & 63, w = t >> 6;
    const int wcol = w << 4;                 // this wave's head = w
    const int ln = lane & 15, lq = lane >> 4;
    const int base = blockIdx.x * 64;

    const short8 b0 = load_bfrag(Wq, wcol, lane, 0);
    const short8 b1 = load_bfrag(Wq, wcol, lane, 1);

    {
        const int r = t >> 2, c4 = (t & 3) << 4;
        int row = base + r; if (row > 49999) row = 49999;
        const float4* p = (const float4*)&h[row * 64 + c4];
        short tmp[16];
        #pragma unroll
        for (int i = 0; i < 4; ++i) {
            float4 x = p[i];
            tmp[4*i+0] = bf16r(x.x); tmp[4*i+1] = bf16r(x.y);
            tmp[4*i+2] = bf16r(x.z); tmp[4*i+3] = bf16r(x.w);
        }
        *(short8*)&sH[r * 72 + c4]     = *(short8*)&tmp[0];
        *(short8*)&sH[r * 72 + c4 + 8] = *(short8*)&tmp[8];
        // NB h-part: node = row>>1, n = row&1 (clamped rows rewrite same data)
        unsigned* nb = NB + ((row >> 1) << 7) + ((row & 1) << 5) + (c4 >> 1);
        *(short8*)(nb)     = *(short8*)&tmp[0];
        *(short8*)(nb + 4) = *(short8*)&tmp[8];
    }
    __syncthreads();

    #pragma unroll
    for (int m = 0; m < 4; ++m) {
        const short* Sm = &sH[(m << 4) * 72];
        short8 a0 = afrag(Sm, lane, 0);
        short8 a1 = afrag(Sm, lane, 1);
        f32x4 acc = {0.f, 0.f, 0.f, 0.f};
        acc = MFMA16(a0, b0, acc);
        acc = MFMA16(a1, b1, acc);
        #pragma unroll
        for (int reg = 0; reg < 4; ++reg) {
            const float qn = sqrtf(red16(acc[reg] * acc[reg]));  // ||Q[row, head w]||
            const float qq = acc[reg] * qn;
            const float qo = __shfl_xor(qq, 1);   // partner column (ln^1)
            const int row = base + (m << 4) + (lq << 2) + reg;
            if (((ln & 1) == 0) && row < 50000) {
                const unsigned u = (unsigned)(unsigned short)bf16r(qq)
                                 | ((unsigned)(unsigned short)bf16r(qo) << 16);
                // qq part: 64 + n*32 + head*8 + col/2
                NB[((row >> 1) << 7) + 64 + ((row & 1) << 5) + (w << 3) + (ln >> 1)] = u;
            }
        }
    }

    if (blockIdx.x == 0) {   // weight fragments for the edge kernel
        fw[(w * 6 + 0) * 64 + lane] = load_bfrag(Wk, wcol, lane, 0);
        fw[(w * 6 + 1) * 64 + lane] = load_bfrag(Wk, wcol, lane, 1);
        fw[(w * 6 + 2) * 64 + lane] = load_bfrag(Wv, wcol, lane, 0);
        fw[(w * 6 + 3) * 64 + lane] = load_bfrag(Wv, wcol, lane, 1);
        fw[(w * 6 + 4) * 64 + lane] = load_bfrag(Wr, wcol, lane, 0);
        fw[(w * 6 + 5) * 64 + lane] = load_bfrag(Wr, wcol, lane, 1);
    }
}

// ---------- edge kernel v4: edge-order, bf16 node-block gathers, atomicMax out ----
// One wave per 8 consecutive edges (coalesced e; 50000*8 == N_EDGES, no masking).
// Gathers: NB[src] 256 B + NB[dst] 512 B per edge (bf16; 12.8 MB working set)
// vs R3's 1.5 KB fp32 against 25.6 MB. Results go straight to out via atomicMax
// on order-preserving uint maps — no msg buffer, no CSR, no reduce pass.
__global__ __launch_bounds__(256, 4) void edge_atomic_kernel(
    const float* __restrict__ e, const int* __restrict__ src,
    const int* __restrict__ dst, const unsigned* __restrict__ NB,
    const short8* __restrict__ fw, unsigned* __restrict__ out_u)
{
    const int t = threadIdx.x;
    const int lane = t & 63;
    const int g = (blockIdx.x << 2) + (t >> 6);   // wave id; 50000 waves exactly
    const int g8 = g << 3;
    const int ln = lane & 15, lq = lane >> 4;
    const int eloc = ln >> 1, nr = ln & 1;        // this lane's A-row: edge slot + group
    const int k0 = lq << 3;

    // ---- A fragments: diff = relu(h[src]-h[dst]) from bf16 node blocks ----
    const int sA = src[g8 + eloc];
    const int dA = dst[g8 + eloc];
    const unsigned* nbs = NB + (sA << 7) + (nr << 5);
    const unsigned* nbd = NB + (dA << 7) + (nr << 5);
    const uint4 su0 = ((const uint4*)nbs)[lq];       // half 0, cols k0..k0+7
    const uint4 su1 = ((const uint4*)nbs)[4 + lq];   // half 1
    const uint4 du0 = ((const uint4*)nbd)[lq];
    const uint4 du1 = ((const uint4*)nbd)[4 + lq];
    uint4 a0u, a1u;
    a0u.x = drelu_pack(su0.x, du0.x); a0u.y = drelu_pack(su0.y, du0.y);
    a0u.z = drelu_pack(su0.z, du0.z); a0u.w = drelu_pack(su0.w, du0.w);
    a1u.x = drelu_pack(su1.x, du1.x); a1u.y = drelu_pack(su1.y, du1.y);
    a1u.z = drelu_pack(su1.z, du1.z); a1u.w = drelu_pack(su1.w, du1.w);
    const short8 afr0 = *(const short8*)&a0u;
    const short8 afr1 = *(const short8*)&a1u;

    // ---- E fragments: coalesced fp32 stream ----
    const float* __restrict__ ep = &e[(((g8 + eloc) << 1) + nr) << 6];
    short8 gfr0, gfr1;
    #pragma unroll
    for (int half = 0; half < 2; ++half) {
        const int cb = (half << 5) + k0;
        const float4 e0 = *(const float4*)&ep[cb];
        const float4 e1 = *(const float4*)&ep[cb + 4];
        short8 tg;
        tg[0] = bfr(e0.x); tg[1] = bfr(e0.y); tg[2] = bfr(e0.z); tg[3] = bfr(e0.w);
        tg[4] = bfr(e1.x); tg[5] = bfr(e1.y); tg[6] = bfr(e1.z); tg[7] = bfr(e1.w);
        if (half == 0) gfr0 = tg; else gfr1 = tg;
    }

    // ---- epilogue metadata: this lane's two C-row edges ----
    // C row rl = lq*4+reg -> edge el = lq*2+(reg>>1), n = reg&1 (validated R1-R3)
    const int e0i = g8 + (lq << 1), e1i = e0i + 1;
    const int d0 = dst[e0i], d1 = dst[e1i];

    // qq gathers from NB (bf16): col = hd*16+ln -> u32 idx hd*8 + ln/2, parity ln&1
    const unsigned* q0p = NB + (d0 << 7) + 64 + (ln >> 1);
    const unsigned* q1p = NB + (d1 << 7) + 64 + (ln >> 1);
    float qvr[4][4];   // [reg][hd], fully unrolled -> registers
    #pragma unroll
    for (int hd = 0; hd < 4; ++hd) {
        qvr[0][hd] = pickbf(q0p[hd << 3],        ln & 1);
        qvr[1][hd] = pickbf(q0p[32 + (hd << 3)], ln & 1);
        qvr[2][hd] = pickbf(q1p[hd << 3],        ln & 1);
        qvr[3][hd] = pickbf(q1p[32 + (hd << 3)], ln & 1);
    }

    // ---- K, V, R for all 4 heads (24 MFMAs; fw L1-hot) ----
    f32x4 aK[4], aV[4], aR[4];
    #pragma unroll
    for (int hd = 0; hd < 4; ++hd) {
        f32x4 k = {0.f, 0.f, 0.f, 0.f}, vv = k, r = k;
        k  = MFMA16(afr0, fw[(hd * 6 + 0) * 64 + lane], k);
        k  = MFMA16(afr1, fw[(hd * 6 + 1) * 64 + lane], k);
        vv = MFMA16(afr0, fw[(hd * 6 + 2) * 64 + lane], vv);
        vv = MFMA16(afr1, fw[(hd * 6 + 3) * 64 + lane], vv);
        r  = MFMA16(gfr0, fw[(hd * 6 + 4) * 64 + lane], r);
        r  = MFMA16(gfr1, fw[(hd * 6 + 5) * 64 + lane], r);
        aK[hd] = k; aV[hd] = vv; aR[hd] = r;
    }

    // ---- msg = (qq * k * ||k|| + r) * v -> atomicMax into out (fire-and-forget) ----
    #pragma unroll
    for (int reg = 0; reg < 4; ++reg) {
        unsigned* ob = out_u + (((reg & 2) ? d1 : d0) << 7) + ((reg & 1) << 6) + ln;
        #pragma unroll
        for (int hd = 0; hd < 4; ++hd) {
            const float kk = aK[hd][reg];
            const float nk = sqrtf(red16(kk * kk));   // ||k|| over head's 16 cols
            const float m = (qvr[reg][hd] * kk * nk + aR[hd][reg]) * aV[hd][reg];
            atomicMax(ob + (hd << 4), fmap(m));
        }
    }
}

// ---------- final: unmap uint -> float in place; untouched (-inf) -> 0 ----------
__global__ __launch_bounds__(256) void final_kernel(unsigned* __restrict__ io) {
    const int i = blockIdx.x * 256 + threadIdx.x;   // grid covers OUT/4 exactly
    uint4* p = (uint4*)io;
    uint4 m = p[i];
    unsigned a, b, c, d;
    a = (m.x & 0x80000000u) ? (m.x ^ 0x80000000u) : ~m.x;
    b = (m.y & 0x80000000u) ? (m.y ^ 0x80000000u) : ~m.y;
    c = (m.z & 0x80000000u) ? (m.z ^ 0x80000000u) : ~m.z;
    d = (m.w & 0x80000000u) ? (m.w ^ 0x80000000u) : ~m.w;
    if (a == 0xFF800000u) a = 0u;   // zero in-degree -> 0 (DGL convention)
    if (b == 0xFF800000u) b = 0u;
    if (c == 0xFF800000u) c = 0u;
    if (d == 0xFF800000u) d = 0u;
    m.x = a; m.y = b; m.z = c; m.w = d;
    p[i] = m;
}

extern "C" void kernel_launch(void* const* d_in, const int* in_sizes, int n_in,
                              void* d_out, int out_size, void* d_ws, size_t ws_size,
                              hipStream_t stream) {
    const float* h  = (const float*)d_in[0];
    const float* e  = (const float*)d_in[1];
    const float* Wq = (const float*)d_in[2];
    const float* Wk = (const float*)d_in[3];
    const float* Wv = (const float*)d_in[4];
    const float* Wr = (const float*)d_in[5];
    const int*   src = (const int*)d_in[6];
    const int*   dst = (const int*)d_in[7];
    float* out = (float*)d_out;

    // workspace layout (4B units), ~12.85 MB total
    unsigned* NB = (unsigned*)d_ws;                    // 25000 * 128 u32 = 3,200,000
    short8*   fw = (short8*)((int*)d_ws + 3200000);    // 1536 x 16B = 6,144 ints

    init_kernel<<<12500, 256, 0, stream>>>((unsigned*)out);            // 3.2M u32
    q_mfma_kernel<<<782, 256, 0, stream>>>(h, Wq, Wk, Wv, Wr, NB, fw);
    edge_atomic_kernel<<<12500, 256, 0, stream>>>(e, src, dst, NB, fw, (unsigned*)out);
    final_kernel<<<3125, 256, 0, stream>>>((unsigned*)out);            // 3125*256*4 u32
}